// Round 4
// baseline (188631.519 us; speedup 1.0000x reference)
//
#include <hip/hip_runtime.h>

#define VOCAB 60
#define EMB   100
#define HID   100
#define SEQN  262144
#define NPROJ 300   // 3*HID

typedef float f32x2 __attribute__((ext_vector_type(2)));
typedef float f32x4 __attribute__((ext_vector_type(4)));

__device__ __forceinline__ float fast_sig(float x) {
    return __builtin_amdgcn_rcpf(1.0f + __builtin_amdgcn_exp2f(-1.442695041f * x));
}
__device__ __forceinline__ float fast_tanh(float x) {
    return 2.0f * __builtin_amdgcn_rcpf(1.0f + __builtin_amdgcn_exp2f(-2.885390082f * x)) - 1.0f;
}

#if __has_builtin(__builtin_elementwise_fma)
#define PKFMA(A, B, C) __builtin_elementwise_fma((A), (B), (C))
#else
__device__ __forceinline__ f32x2 pkfma_(f32x2 a, f32x2 b, f32x2 c) {
    f32x2 r; r.x = fmaf(a.x, b.x, c.x); r.y = fmaf(a.y, b.y, c.y); return r;
}
#define PKFMA pkfma_
#endif

// f32x2 slice of an f32x4 at parse-time-constant index I (0 or 2).
#define SH2(V, I) __builtin_shufflevector((V), (V), (I), (I) + 1)

// proj[v][j] = emb[v]·w_ih[j] + b_ih[j] + (j<200 ? b_hh[j] : 0)
__global__ void precompute_kernel(const float* __restrict__ emb,
                                  const float* __restrict__ w_ih,
                                  const float* __restrict__ b_ih,
                                  const float* __restrict__ b_hh,
                                  float* __restrict__ proj)
{
    int idx = blockIdx.x * blockDim.x + threadIdx.x;
    if (idx < VOCAB * NPROJ) {
        int v = idx / NPROJ, j = idx - v * NPROJ;
        float acc = b_ih[j] + (j < 2 * HID ? b_hh[j] : 0.0f);
        const float* er = emb  + v * EMB;
        const float* wr = w_ih + j * EMB;
        #pragma unroll 4
        for (int k = 0; k < EMB; ++k) acc = fmaf(er[k], wr[k], acc);
        proj[idx] = acc;
    }
}

// 384 threads = 6 waves, one CU.
// waves 0-3: row R=tid, k in [0,100).  wave 4: R=256+lane (lane<44), k in [0,52).
// wave 5: same rows, k in [52,100).  u[] holds full values for R<256 and two
// partials (R and R+44) for R>=256. h per-wave private in LDS; ONE barrier/step.
// Weights: 25 named f32x4 SSA values (4-reg tuples -> RA-friendly, no scratch).
// __launch_bounds__(384, 2): min 2 waves/EU -> 256-VGPR budget.
__global__ __launch_bounds__(384, 2) __attribute__((amdgpu_waves_per_eu(2, 2)))
void gru_seq_kernel(const int*   __restrict__ x,
                    const float* __restrict__ b_hh,
                    const float* __restrict__ proj,
                    const float* __restrict__ w_hh,
                    float* __restrict__ out)
{
    __shared__ __align__(16) float h_priv[6][104];
    __shared__ float u[2][352];

    const int tid  = threadIdx.x;
    const int wave = tid >> 6;
    const int lane = tid & 63;

    const int  l1   = (lane < 36) ? lane : 35;   // second h index (clamped)
    const bool has1 = (lane < 36);

    int  R;
    bool active;
    if (wave < 4) { R = tid; active = true; }
    else          { R = 256 + ((lane < 44) ? lane : 43); active = (lane < 44); }
    const int uidx = (wave == 5) ? (R + 44) : R;   // partial1 slot at R+44

    // Weight row in 25 named f32x4 registers. Rows are 400 B -> 16 B aligned.
    const float* wrow = w_hh + R * HID;
    f32x4 w0,  w1,  w2,  w3,  w4,  w5,  w6,  w7,  w8,  w9,  w10, w11, w12,
          w13, w14, w15, w16, w17, w18, w19, w20, w21, w22, w23, w24;
#define WLOAD(J) w##J = *(const f32x4*)(wrow + 4 * J);
    WLOAD(0)  WLOAD(1)  WLOAD(2)  WLOAD(3)  WLOAD(4)
    WLOAD(5)  WLOAD(6)  WLOAD(7)  WLOAD(8)  WLOAD(9)
    WLOAD(10) WLOAD(11) WLOAD(12) WLOAD(13) WLOAD(14)
    WLOAD(15) WLOAD(16) WLOAD(17) WLOAD(18) WLOAD(19)
    WLOAD(20) WLOAD(21) WLOAD(22) WLOAD(23) WLOAD(24)
#undef WLOAD

// Weight chunk J covers k in [4J, 4J+4): one b128 broadcast of h + 2 pk-FMAs.
#define HSTEP(J, A0, A1) {                                \
    f32x4 hv_ = *(const f32x4*)(hp + 4 * J);              \
    A0 = PKFMA(SH2(w##J, 0), SH2(hv_, 0), A0);            \
    A1 = PKFMA(SH2(w##J, 2), SH2(hv_, 2), A1); }

    const bool  needs_proj = (wave < 4) && (R < 200);
    const float init_const = (wave == 5) ? 0.0f
                           : ((wave == 4 || R >= 200) ? b_hh[R] : 0.0f);

    h_priv[wave][lane] = 0.0f;
    if (lane < 40) h_priv[wave][64 + lane] = 0.0f;
    float hold0 = 0.0f, hold1 = 0.0f;

    // Software-pipelined token/proj lookups (1 step of slack, L2-resident).
    int tok = x[0];
    float xpA = needs_proj ? proj[tok * NPROJ + R] : init_const;
    float xn0 = proj[tok * NPROJ + 200 + lane];
    float xn1 = proj[tok * NPROJ + 264 + l1];
    int tok_next = x[1];

    __syncthreads();

    for (int t = 0; t < SEQN; ++t) {
        const int buf = t & 1;

        // Prefetch step t+1 inputs.
        int   tok_nn = x[(t + 2 < SEQN) ? (t + 2) : (SEQN - 1)];
        float xpA_n  = needs_proj ? proj[tok_next * NPROJ + R] : init_const;
        float xn0_n  = proj[tok_next * NPROJ + 200 + lane];
        float xn1_n  = proj[tok_next * NPROJ + 264 + l1];

        // ---- Phase A: u[R] = init + W_hh[R]·h over this thread's k-range ----
        const float* hp = h_priv[wave];
        f32x2 acc0 = {xpA, 0.0f}, acc1 = {0.0f, 0.0f},
              acc2 = {0.0f, 0.0f}, acc3 = {0.0f, 0.0f};
        if (wave < 4) {               // k in [0,100): chunks 0..24
            HSTEP(0,  acc0, acc1) HSTEP(1,  acc2, acc3)
            HSTEP(2,  acc0, acc1) HSTEP(3,  acc2, acc3)
            HSTEP(4,  acc0, acc1) HSTEP(5,  acc2, acc3)
            HSTEP(6,  acc0, acc1) HSTEP(7,  acc2, acc3)
            HSTEP(8,  acc0, acc1) HSTEP(9,  acc2, acc3)
            HSTEP(10, acc0, acc1) HSTEP(11, acc2, acc3)
            HSTEP(12, acc0, acc1) HSTEP(13, acc2, acc3)
            HSTEP(14, acc0, acc1) HSTEP(15, acc2, acc3)
            HSTEP(16, acc0, acc1) HSTEP(17, acc2, acc3)
            HSTEP(18, acc0, acc1) HSTEP(19, acc2, acc3)
            HSTEP(20, acc0, acc1) HSTEP(21, acc2, acc3)
            HSTEP(22, acc0, acc1) HSTEP(23, acc2, acc3)
            HSTEP(24, acc0, acc1)
        } else if (wave == 4) {       // k in [0,52): chunks 0..12
            HSTEP(0,  acc0, acc1) HSTEP(1,  acc2, acc3)
            HSTEP(2,  acc0, acc1) HSTEP(3,  acc2, acc3)
            HSTEP(4,  acc0, acc1) HSTEP(5,  acc2, acc3)
            HSTEP(6,  acc0, acc1) HSTEP(7,  acc2, acc3)
            HSTEP(8,  acc0, acc1) HSTEP(9,  acc2, acc3)
            HSTEP(10, acc0, acc1) HSTEP(11, acc2, acc3)
            HSTEP(12, acc0, acc1)
        } else {                      // k in [52,100): chunks 13..24
            HSTEP(13, acc0, acc1) HSTEP(14, acc2, acc3)
            HSTEP(15, acc0, acc1) HSTEP(16, acc2, acc3)
            HSTEP(17, acc0, acc1) HSTEP(18, acc2, acc3)
            HSTEP(19, acc0, acc1) HSTEP(20, acc2, acc3)
            HSTEP(21, acc0, acc1) HSTEP(22, acc2, acc3)
            HSTEP(23, acc0, acc1) HSTEP(24, acc2, acc3)
        }
        f32x2 s2 = (acc0 + acc1) + (acc2 + acc3);
        if (active) u[buf][uidx] = s2.x + s2.y;
        __syncthreads();   // the ONLY barrier per step

        // ---- Phase B (redundant per wave): gates + h update ----
        const float* ub = u[buf];
        float ur0 = ub[lane];
        float uz0 = ub[100 + lane];
        float un0 = ub[200 + lane];
        if (lane >= 56) un0 += ub[244 + lane];     // rows >=256: add partial1
        float ur1 = ub[64 + l1];
        float uz1 = ub[164 + l1];
        float un1 = ub[264 + l1] + ub[308 + l1];   // always split rows

        float r0  = fast_sig(ur0);
        float z0  = fast_sig(uz0);
        float n0  = fast_tanh(xn0 + r0 * un0);
        float hn0 = n0 + z0 * (hold0 - n0);

        float r1  = fast_sig(ur1);
        float z1  = fast_sig(uz1);
        float n1  = fast_tanh(xn1 + r1 * un1);
        float hn1 = n1 + z1 * (hold1 - n1);

        h_priv[wave][lane] = hn0;
        hold0 = hn0;
        if (has1) { h_priv[wave][64 + lane] = hn1; hold1 = hn1; }

        tok = tok_next;  tok_next = tok_nn;
        xpA = xpA_n;  xn0 = xn0_n;  xn1 = xn1_n;
    }

    if (wave == 0) {
        out[lane] = hold0;                 // h[0..63]
        if (has1) out[64 + lane] = hold1;  // h[64..99]
    }
}

extern "C" void kernel_launch(void* const* d_in, const int* in_sizes, int n_in,
                              void* d_out, int out_size, void* d_ws, size_t ws_size,
                              hipStream_t stream)
{
    const int*   x    = (const int*)  d_in[0];
    const float* emb  = (const float*)d_in[1];
    const float* w_ih = (const float*)d_in[2];
    const float* w_hh = (const float*)d_in[3];
    const float* b_ih = (const float*)d_in[4];
    const float* b_hh = (const float*)d_in[5];
    float* out = (float*)d_out;

    float* proj = (float*)d_ws;              // 60*300 f32 = 72 KB scratch

    const int total = VOCAB * NPROJ;         // 18000
    precompute_kernel<<<(total + 255) / 256, 256, 0, stream>>>(
        emb, w_ih, b_ih, b_hh, proj);
    gru_seq_kernel<<<1, 384, 0, stream>>>(x, b_hh, proj, w_hh, out);
}

// Round 5
// 186794.958 us; speedup vs baseline: 1.0098x; 1.0098x over previous
//
#include <hip/hip_runtime.h>

#define VOCAB 60
#define EMB   100
#define HID   100
#define SEQN  262144
#define NPROJ 300   // 3*HID

typedef float f32x2 __attribute__((ext_vector_type(2)));
typedef float f32x4 __attribute__((ext_vector_type(4)));

__device__ __forceinline__ float fast_sig(float x) {
    return __builtin_amdgcn_rcpf(1.0f + __builtin_amdgcn_exp2f(-1.442695041f * x));
}
__device__ __forceinline__ float fast_tanh(float x) {
    return 2.0f * __builtin_amdgcn_rcpf(1.0f + __builtin_amdgcn_exp2f(-2.885390082f * x)) - 1.0f;
}

#if __has_builtin(__builtin_elementwise_fma)
#define PKFMA(A, B, C) __builtin_elementwise_fma((A), (B), (C))
#else
__device__ __forceinline__ f32x2 pkfma_(f32x2 a, f32x2 b, f32x2 c) {
    f32x2 r; r.x = fmaf(a.x, b.x, c.x); r.y = fmaf(a.y, b.y, c.y); return r;
}
#define PKFMA pkfma_
#endif

// f32x2 slice of an f32x4 at parse-time-constant index I (0 or 2).
#define SH2(V, I) __builtin_shufflevector((V), (V), (I), (I) + 1)

// proj[v][j] = emb[v]·w_ih[j] + b_ih[j] + (j<200 ? b_hh[j] : 0)
__global__ void precompute_kernel(const float* __restrict__ emb,
                                  const float* __restrict__ w_ih,
                                  const float* __restrict__ b_ih,
                                  const float* __restrict__ b_hh,
                                  float* __restrict__ proj)
{
    int idx = blockIdx.x * blockDim.x + threadIdx.x;
    if (idx < VOCAB * NPROJ) {
        int v = idx / NPROJ, j = idx - v * NPROJ;
        float acc = b_ih[j] + (j < 2 * HID ? b_hh[j] : 0.0f);
        const float* er = emb  + v * EMB;
        const float* wr = w_ih + j * EMB;
        #pragma unroll 4
        for (int k = 0; k < EMB; ++k) acc = fmaf(er[k], wr[k], acc);
        proj[idx] = acc;
    }
}

// 384 threads = 6 waves, one CU.
// waves 0-3: row R=tid, k in [0,100).  wave 4: R=256+lane (lane<44), k in [0,52).
// wave 5: same rows, k in [52,100).  u[] holds full values for R<256 and two
// partials (R and R+44) for R>=256. h per-wave private in LDS; ONE barrier/step.
// Weights: 25 named f32x4 values forced through an opaque asm passthrough so
// the RA cannot rematerialize them as per-iteration reloads (the round-4 bug).
__global__ __launch_bounds__(384, 2) __attribute__((amdgpu_waves_per_eu(2, 2)))
void gru_seq_kernel(const int*   __restrict__ x,
                    const float* __restrict__ b_hh,
                    const float* __restrict__ proj,
                    const float* __restrict__ w_hh,
                    float* __restrict__ out)
{
    __shared__ __align__(16) float h_priv[6][104];
    __shared__ float u[2][352];

    const int tid  = threadIdx.x;
    const int wave = tid >> 6;
    const int lane = tid & 63;

    const int  l1   = (lane < 36) ? lane : 35;   // second h index (clamped)
    const bool has1 = (lane < 36);

    int  R;
    bool active;
    if (wave < 4) { R = tid; active = true; }
    else          { R = 256 + ((lane < 44) ? lane : 43); active = (lane < 44); }
    const int uidx = (wave == 5) ? (R + 44) : R;   // partial1 slot at R+44

    // Weight row in 25 named f32x4 registers. Rows are 400 B -> 16 B aligned.
    const float* wrow = w_hh + R * HID;
    f32x4 w0,  w1,  w2,  w3,  w4,  w5,  w6,  w7,  w8,  w9,  w10, w11, w12,
          w13, w14, w15, w16, w17, w18, w19, w20, w21, w22, w23, w24;
#define WLOAD(J) w##J = *(const f32x4*)(wrow + 4 * J);
    WLOAD(0)  WLOAD(1)  WLOAD(2)  WLOAD(3)  WLOAD(4)
    WLOAD(5)  WLOAD(6)  WLOAD(7)  WLOAD(8)  WLOAD(9)
    WLOAD(10) WLOAD(11) WLOAD(12) WLOAD(13) WLOAD(14)
    WLOAD(15) WLOAD(16) WLOAD(17) WLOAD(18) WLOAD(19)
    WLOAD(20) WLOAD(21) WLOAD(22) WLOAD(23) WLOAD(24)
#undef WLOAD

    // THE FIX: opaque passthrough. Each w##J is now defined by an asm, not a
    // load -> LLVM cannot rematerialize it as a per-iteration reload; it must
    // keep the values in VGPRs (budget 256 via waves_per_eu(2,2)).
    asm("" : "+v"(w0), "+v"(w1), "+v"(w2), "+v"(w3), "+v"(w4));
    asm("" : "+v"(w5), "+v"(w6), "+v"(w7), "+v"(w8), "+v"(w9));
    asm("" : "+v"(w10), "+v"(w11), "+v"(w12), "+v"(w13), "+v"(w14));
    asm("" : "+v"(w15), "+v"(w16), "+v"(w17), "+v"(w18), "+v"(w19));
    asm("" : "+v"(w20), "+v"(w21), "+v"(w22), "+v"(w23), "+v"(w24));

// Weight chunk J covers k in [4J, 4J+4): one b128 broadcast of h + 2 pk-FMAs.
#define HSTEP(J, A0, A1) {                                \
    f32x4 hv_ = *(const f32x4*)(hp + 4 * J);              \
    A0 = PKFMA(SH2(w##J, 0), SH2(hv_, 0), A0);            \
    A1 = PKFMA(SH2(w##J, 2), SH2(hv_, 2), A1); }

    const bool  needs_proj = (wave < 4) && (R < 200);
    const float init_const = (wave == 5) ? 0.0f
                           : ((wave == 4 || R >= 200) ? b_hh[R] : 0.0f);

    h_priv[wave][lane] = 0.0f;
    if (lane < 40) h_priv[wave][64 + lane] = 0.0f;
    float hold0 = 0.0f, hold1 = 0.0f;

    // Software-pipelined token/proj lookups (1 step of slack, L2-resident).
    int tok = x[0];
    float xpA = needs_proj ? proj[tok * NPROJ + R] : init_const;
    float xn0 = proj[tok * NPROJ + 200 + lane];
    float xn1 = proj[tok * NPROJ + 264 + l1];
    int tok_next = x[1];

    __syncthreads();

    for (int t = 0; t < SEQN; ++t) {
        const int buf = t & 1;

        // Prefetch step t+1 inputs.
        int   tok_nn = x[(t + 2 < SEQN) ? (t + 2) : (SEQN - 1)];
        float xpA_n  = needs_proj ? proj[tok_next * NPROJ + R] : init_const;
        float xn0_n  = proj[tok_next * NPROJ + 200 + lane];
        float xn1_n  = proj[tok_next * NPROJ + 264 + l1];

        // ---- Phase A: u[R] = init + W_hh[R]·h over this thread's k-range ----
        const float* hp = h_priv[wave];
        f32x2 acc0 = {xpA, 0.0f}, acc1 = {0.0f, 0.0f},
              acc2 = {0.0f, 0.0f}, acc3 = {0.0f, 0.0f};
        if (wave < 4) {               // k in [0,100): chunks 0..24
            HSTEP(0,  acc0, acc1) HSTEP(1,  acc2, acc3)
            HSTEP(2,  acc0, acc1) HSTEP(3,  acc2, acc3)
            HSTEP(4,  acc0, acc1) HSTEP(5,  acc2, acc3)
            HSTEP(6,  acc0, acc1) HSTEP(7,  acc2, acc3)
            HSTEP(8,  acc0, acc1) HSTEP(9,  acc2, acc3)
            HSTEP(10, acc0, acc1) HSTEP(11, acc2, acc3)
            HSTEP(12, acc0, acc1) HSTEP(13, acc2, acc3)
            HSTEP(14, acc0, acc1) HSTEP(15, acc2, acc3)
            HSTEP(16, acc0, acc1) HSTEP(17, acc2, acc3)
            HSTEP(18, acc0, acc1) HSTEP(19, acc2, acc3)
            HSTEP(20, acc0, acc1) HSTEP(21, acc2, acc3)
            HSTEP(22, acc0, acc1) HSTEP(23, acc2, acc3)
            HSTEP(24, acc0, acc1)
        } else if (wave == 4) {       // k in [0,52): chunks 0..12
            HSTEP(0,  acc0, acc1) HSTEP(1,  acc2, acc3)
            HSTEP(2,  acc0, acc1) HSTEP(3,  acc2, acc3)
            HSTEP(4,  acc0, acc1) HSTEP(5,  acc2, acc3)
            HSTEP(6,  acc0, acc1) HSTEP(7,  acc2, acc3)
            HSTEP(8,  acc0, acc1) HSTEP(9,  acc2, acc3)
            HSTEP(10, acc0, acc1) HSTEP(11, acc2, acc3)
            HSTEP(12, acc0, acc1)
        } else {                      // k in [52,100): chunks 13..24
            HSTEP(13, acc0, acc1) HSTEP(14, acc2, acc3)
            HSTEP(15, acc0, acc1) HSTEP(16, acc2, acc3)
            HSTEP(17, acc0, acc1) HSTEP(18, acc2, acc3)
            HSTEP(19, acc0, acc1) HSTEP(20, acc2, acc3)
            HSTEP(21, acc0, acc1) HSTEP(22, acc2, acc3)
            HSTEP(23, acc0, acc1) HSTEP(24, acc2, acc3)
        }
        f32x2 s2 = (acc0 + acc1) + (acc2 + acc3);
        if (active) u[buf][uidx] = s2.x + s2.y;
        __syncthreads();   // the ONLY barrier per step

        // ---- Phase B (redundant per wave): gates + h update ----
        const float* ub = u[buf];
        float ur0 = ub[lane];
        float uz0 = ub[100 + lane];
        float un0 = ub[200 + lane];
        if (lane >= 56) un0 += ub[244 + lane];     // rows >=256: add partial1
        float ur1 = ub[64 + l1];
        float uz1 = ub[164 + l1];
        float un1 = ub[264 + l1] + ub[308 + l1];   // always split rows

        float r0  = fast_sig(ur0);
        float z0  = fast_sig(uz0);
        float n0  = fast_tanh(xn0 + r0 * un0);
        float hn0 = n0 + z0 * (hold0 - n0);

        float r1  = fast_sig(ur1);
        float z1  = fast_sig(uz1);
        float n1  = fast_tanh(xn1 + r1 * un1);
        float hn1 = n1 + z1 * (hold1 - n1);

        h_priv[wave][lane] = hn0;
        hold0 = hn0;
        if (has1) { h_priv[wave][64 + lane] = hn1; hold1 = hn1; }

        tok = tok_next;  tok_next = tok_nn;
        xpA = xpA_n;  xn0 = xn0_n;  xn1 = xn1_n;
    }

    if (wave == 0) {
        out[lane] = hold0;                 // h[0..63]
        if (has1) out[64 + lane] = hold1;  // h[64..99]
    }
}

extern "C" void kernel_launch(void* const* d_in, const int* in_sizes, int n_in,
                              void* d_out, int out_size, void* d_ws, size_t ws_size,
                              hipStream_t stream)
{
    const int*   x    = (const int*)  d_in[0];
    const float* emb  = (const float*)d_in[1];
    const float* w_ih = (const float*)d_in[2];
    const float* w_hh = (const float*)d_in[3];
    const float* b_ih = (const float*)d_in[4];
    const float* b_hh = (const float*)d_in[5];
    float* out = (float*)d_out;

    float* proj = (float*)d_ws;              // 60*300 f32 = 72 KB scratch

    const int total = VOCAB * NPROJ;         // 18000
    precompute_kernel<<<(total + 255) / 256, 256, 0, stream>>>(
        emb, w_ih, b_ih, b_hh, proj);
    gru_seq_kernel<<<1, 384, 0, stream>>>(x, b_hh, proj, w_hh, out);
}